// Round 5
// baseline (3610.714 us; speedup 1.0000x reference)
//
#include <hip/hip_runtime.h>

// LSTMClassification: B=64, T=512, IN=128, H=512, 2 layers + FC(512->1)
// Fused persistent-LSTM: 128 WGs (0-63 = layer0, 64-127 = layer1), 1-step skew.
// WG w owns h-columns [8w,8w+8) => 32 gate rows in LDS (bf16, XOR-swizzled).
// h exchange via cache-bypassing AGENT-scope ops in WG-block-major layout
// (coalesced 1KB producer blocks / 256B consumer runs -- round-4 win).
// Round-5 change: sync via per-step counters with 8 sub-counters packed in ONE
// 64B line; polling wave = ONE MALL transaction per poll (round-4 polls were
// 64 x 64B-strided transactions = ~1.4 TB/s of poll congestion inflating every
// critical-path round trip). L0 recurrence reads h0_all[t-1] directly (hs0
// parity buffer removed; one store per tid in publish).

#define NWG 64
#define NB 64      // batch
#define NT 512     // seq len
#define NH 512     // hidden

typedef float f32x4 __attribute__((ext_vector_type(4)));
typedef __bf16 bf16x4 __attribute__((ext_vector_type(4)));
typedef __bf16 bf16x8 __attribute__((ext_vector_type(8)));

__device__ __forceinline__ bf16x4 ld8_bypass(const __bf16* p) {
    unsigned long long v = __hip_atomic_load((const unsigned long long*)p,
                                             __ATOMIC_RELAXED, __HIP_MEMORY_SCOPE_AGENT);
    bf16x4 r; __builtin_memcpy(&r, &v, 8); return r;
}

__device__ __forceinline__ void st8_bypass(__bf16* p, unsigned long long v) {
    __hip_atomic_store((unsigned long long*)p, v, __ATOMIC_RELAXED, __HIP_MEMORY_SCOPE_AGENT);
}

// Poll step-t counter: 8 sub-counters in one 64B line; lane l watches sub (l&7).
// One coalesced MALL transaction per iteration; done when every sub >= 8.
__device__ __forceinline__ void wait_cnt(const unsigned* cnt, int t, int lane) {
    const unsigned* p = cnt + t * 16 + (lane & 7);
    int guard = 0;
    for (;;) {
        unsigned f = __hip_atomic_load((unsigned*)p, __ATOMIC_RELAXED,
                                       __HIP_MEMORY_SCOPE_AGENT);
        if (__all((int)(f >= 8u))) break;
        if (++guard > (1 << 17)) break;   // safety: never hard-hang
    }
}

__global__ void prep_kernel(unsigned short* hinit, unsigned short* hs1, unsigned* cnts) {
    int i = blockIdx.x * blockDim.x + threadIdx.x;
    if (i < NWG * NB * 8) hinit[i] = 0;            // zero h_{-1} for L0
    if (i < 2 * NWG * NB * 8) hs1[i] = 0;          // L1 parity buffers
    if (i < 2 * NT * 16) cnts[i] = 0;              // per-step sub-counters, both layers
}

template<int KIH, int IS_L0>
__device__ __forceinline__ void layer_body(
    char* Wl, float (*gbuf)[36], float (*c_lds)[8], unsigned short (*hstage)[8],
    int wg,
    const float* __restrict__ W_ih, const float* __restrict__ W_hh,
    const float* __restrict__ b_ih, const float* __restrict__ b_hh,
    const float* __restrict__ x_f32,       // L0: x [NB][NT][KIH] fp32 (cached)
    const __bf16* __restrict__ h_in_all,   // L1: h0_all [NT][NWG][NB][8] (bypass)
    __bf16* __restrict__ h_out_all,        // L0: h0_all [NT][NWG][NB][8] (bypass)
    const __bf16* __restrict__ hinit,      // L0: zero block [NWG][NB][8]
    __bf16* __restrict__ hbuf,             // L1: [2][NWG][NB][8] parity buffer
    float* __restrict__ h_final,           // L1: [NB][NH] fp32
    unsigned* __restrict__ cnt_self,       // [NT*16] this layer's step counters
    const unsigned* __restrict__ cnt_dep)  // [NT*16] producer layer's counters
{
    constexpr int KTOT = KIH + NH;
    constexpr int NCH_A = KIH / 32;
    constexpr int NCH_B = NH / 32;         // 16
    constexpr int ROWB = KTOT * 2;
    constexpr int BLK = NB * 8;            // elements per WG block (512)

    const int tid = threadIdx.x;
    const int hcol0 = wg * 8;

    // ---- stage weight slice into LDS (bf16, row-XOR swizzle) ----
    {
        constexpr int CPR = KTOT / 8;
        for (int cid = tid; cid < 32 * CPR; cid += 512) {
            const int r = cid / CPR;
            const int k0 = (cid - r * CPR) * 8;
            const int grow = (r >> 3) * NH + hcol0 + (r & 7);
            const float* src = (k0 < KIH) ? (W_ih + (size_t)grow * KIH + k0)
                                          : (W_hh + (size_t)grow * NH + (k0 - KIH));
            union { __bf16 h[8]; uint4 u; } tmp;
            #pragma unroll
            for (int j = 0; j < 8; ++j) tmp.h[j] = (__bf16)src[j];
            const unsigned off = (unsigned)(r * ROWB) +
                (((unsigned)(2 * k0)) ^ ((unsigned)((r & 7) << 4)));
            *(uint4*)(Wl + off) = tmp.u;
        }
    }

    // epilogue mapping + folded biases
    const int eb = tid >> 3, ec = tid & 7;
    const int hcE = hcol0 + ec;
    const float bI = b_ih[hcE]          + b_hh[hcE];
    const float bF = b_ih[NH + hcE]     + b_hh[NH + hcE];
    const float bG = b_ih[2 * NH + hcE] + b_hh[2 * NH + hcE];
    const float bO = b_ih[3 * NH + hcE] + b_hh[3 * NH + hcE];
    c_lds[eb][ec] = 0.0f;
    __syncthreads();

    // MFMA mapping: 8 waves = 4 batch-tiles x 2 gate-tiles of 16x16
    const int lane = tid & 63;
    const int wid = tid >> 6;
    const int bt = (wid & 3) * 16;
    const int gt = (wid >> 2) * 16;
    const int arow = bt + (lane & 15);
    const int q4 = ((lane >> 4) & 3) * 4;
    const int brow = gt + (lane & 15);
    const char* wrow = Wl + brow * ROWB;
    const unsigned bsz = (unsigned)((brow & 7) << 4);

    // block-layout A-fragment offsets: col = 32*kk + (q4>>3)*8 + (q4&4) + j
    const int aoff = arow * 8 + (q4 & 4);      // within-block element offset
    const int bsub = (q4 >> 3);                // sub-block select (0/1)

    auto wfrag = [&](int k0) -> bf16x8 {
        const bf16x4 blo = *(const bf16x4*)(wrow + (((unsigned)(2 * (k0 + q4))) ^ bsz));
        const bf16x4 bhi = *(const bf16x4*)(wrow + (((unsigned)(2 * (k0 + 16 + q4))) ^ bsz));
        return __builtin_shufflevector(blo, bhi, 0, 1, 2, 3, 4, 5, 6, 7);
    };

    for (int t = 0; t < NT; ++t) {
        // L0: recurrence reads h0_all[t-1] (hinit at t=0); L1: parity buffer
        const __bf16* __restrict__ hprev;
        __bf16* __restrict__ hout;
        if constexpr (IS_L0 != 0) {
            hprev = (t == 0) ? hinit : (h_out_all + (size_t)(t - 1) * NWG * BLK);
            hout = h_out_all + (size_t)t * NWG * BLK;
        } else {
            hprev = hbuf + (size_t)(t & 1) * NWG * BLK;
            hout = hbuf + (size_t)((t + 1) & 1) * NWG * BLK;
        }

        f32x4 accA0 = {0.f,0.f,0.f,0.f}, accA1 = {0.f,0.f,0.f,0.f};
        f32x4 accB0 = {0.f,0.f,0.f,0.f}, accB1 = {0.f,0.f,0.f,0.f};

        if constexpr (IS_L0 != 0) {
            // phase A from x (cached, no dependency) BEFORE the wait
            const float* xb = x_f32 + ((size_t)arow * NT + t) * KIH;
            bf16x8 av[NCH_A];
            #pragma unroll
            for (int kk = 0; kk < NCH_A; ++kk) {
                const float4 lo = *(const float4*)(xb + kk * 32 + q4);
                const float4 hi = *(const float4*)(xb + kk * 32 + 16 + q4);
                const bf16x4 alo = {(__bf16)lo.x, (__bf16)lo.y, (__bf16)lo.z, (__bf16)lo.w};
                const bf16x4 ahi = {(__bf16)hi.x, (__bf16)hi.y, (__bf16)hi.z, (__bf16)hi.w};
                av[kk] = __builtin_shufflevector(alo, ahi, 0, 1, 2, 3, 4, 5, 6, 7);
            }
            #pragma unroll
            for (int kk = 0; kk < NCH_A; ++kk) {
                f32x4& a = (kk & 1) ? accA1 : accA0;
                a = __builtin_amdgcn_mfma_f32_16x16x32_bf16(av[kk], wfrag(kk * 32), a, 0, 0, 0);
            }
            if (t > 0 && wid == 0) wait_cnt(cnt_self, t - 1, lane);
            __syncthreads();
        } else {
            // L1: wave0 waits for producer step t; wave1 for own recurrence t-1
            if (wid == 0) wait_cnt(cnt_dep, t, lane);
            if (wid == 1 && t > 0) wait_cnt(cnt_self, t - 1, lane);
            __syncthreads();
        }

        // ---- preload A-fragments (block layout, coalesced bypass loads) ----
        bf16x4 aBlo[NCH_B], aBhi[NCH_B];
        #pragma unroll
        for (int kk = 0; kk < NCH_B; ++kk) {
            const __bf16* base = hprev + (4 * kk + bsub) * BLK + aoff;
            aBlo[kk] = ld8_bypass(base);
            aBhi[kk] = ld8_bypass(base + 2 * BLK);
        }
        if constexpr (IS_L0 == 0) {
            const __bf16* hA = h_in_all + (size_t)t * NWG * BLK;
            bf16x4 aAlo[NCH_A], aAhi[NCH_A];
            #pragma unroll
            for (int kk = 0; kk < NCH_A; ++kk) {
                const __bf16* base = hA + (4 * kk + bsub) * BLK + aoff;
                aAlo[kk] = ld8_bypass(base);
                aAhi[kk] = ld8_bypass(base + 2 * BLK);
            }
            #pragma unroll
            for (int kk = 0; kk < NCH_A; ++kk) {
                f32x4& a = (kk & 1) ? accA1 : accA0;
                const bf16x8 av = __builtin_shufflevector(aAlo[kk], aAhi[kk], 0,1,2,3,4,5,6,7);
                a = __builtin_amdgcn_mfma_f32_16x16x32_bf16(av, wfrag(kk * 32), a, 0, 0, 0);
            }
        }
        #pragma unroll
        for (int kk = 0; kk < NCH_B; ++kk) {
            f32x4& a = (kk & 1) ? accB1 : accB0;
            const bf16x8 av = __builtin_shufflevector(aBlo[kk], aBhi[kk], 0,1,2,3,4,5,6,7);
            a = __builtin_amdgcn_mfma_f32_16x16x32_bf16(av, wfrag(KIH + kk * 32), a, 0, 0, 0);
        }

        const f32x4 acc = (accA0 + accA1) + (accB0 + accB1);

        // scatter C tile (row = batch = (lane>>4)*4+i, col = gate = lane&15)
        #pragma unroll
        for (int i = 0; i < 4; ++i)
            gbuf[bt + ((lane >> 4) & 3) * 4 + i][gt + (lane & 15)] = acc[i];
        __syncthreads();

        // LSTM cell, fp32 (gate order i, f, g, o)
        {
            const float gi = gbuf[eb][ec]      + bI;
            const float gf = gbuf[eb][8 + ec]  + bF;
            const float gg = gbuf[eb][16 + ec] + bG;
            const float go = gbuf[eb][24 + ec] + bO;
            const float ii = 1.0f / (1.0f + __expf(-gi));
            const float ff = 1.0f / (1.0f + __expf(-gf));
            const float g2 = 2.0f / (1.0f + __expf(-2.0f * gg)) - 1.0f;   // tanh
            const float oo = 1.0f / (1.0f + __expf(-go));
            const float cn = ff * c_lds[eb][ec] + ii * g2;
            const float th = 2.0f / (1.0f + __expf(-2.0f * cn)) - 1.0f;
            const float hn = oo * th;
            c_lds[eb][ec] = cn;
            const __bf16 hb = (__bf16)hn;
            unsigned short ub;
            __builtin_memcpy(&ub, &hb, 2);
            hstage[eb][ec] = ub;
            if constexpr (IS_L0 == 0) {
                if (t == NT - 1) h_final[(size_t)eb * NH + hcol0 + ec] = hn;
            }
        }
        __syncthreads();

        // publish this WG's contiguous 1KB block: 128 threads x 8B bypass stores
        if (tid < 128) {
            unsigned long long v;
            __builtin_memcpy(&v, &hstage[tid >> 1][(tid & 1) * 4], 8);
            st8_bypass(hout + (size_t)wg * BLK + tid * 4, v);
        }
        asm volatile("s_waitcnt vmcnt(0)" ::: "memory");   // drain own stores
        __syncthreads();                                   // all waves drained
        if (tid == 0)
            __hip_atomic_fetch_add(&cnt_self[t * 16 + (wg & 7)], 1u,
                                   __ATOMIC_RELAXED, __HIP_MEMORY_SCOPE_AGENT);
    }
}

__launch_bounds__(512, 2)
__global__ void lstm_fused_kernel(
    const float* W_ih0, const float* W_hh0, const float* b_ih0, const float* b_hh0,
    const float* W_ih1, const float* W_hh1, const float* b_ih1, const float* b_hh1,
    const float* x, __bf16* h0_all, __bf16* hinit, __bf16* hs1,
    float* hfin, unsigned* cnt0, unsigned* cnt1)
{
    __shared__ __align__(16) char Wl[32 * 2048];    // max(40KB, 64KB)
    __shared__ float gbuf[64][36];
    __shared__ float c_lds[64][8];
    __shared__ unsigned short hstage[64][8];

    if (blockIdx.x < NWG) {
        layer_body<128, 1>(Wl, gbuf, c_lds, hstage, blockIdx.x,
                           W_ih0, W_hh0, b_ih0, b_hh0,
                           x, nullptr, h0_all, hinit, nullptr, nullptr, cnt0, nullptr);
    } else {
        layer_body<512, 0>(Wl, gbuf, c_lds, hstage, blockIdx.x - NWG,
                           W_ih1, W_hh1, b_ih1, b_hh1,
                           nullptr, h0_all, nullptr, nullptr, hs1, hfin, cnt1, cnt0);
    }
}

__global__ void fc_kernel(const float* __restrict__ hfin,
                          const float* __restrict__ w_fc,
                          const float* __restrict__ b_fc,
                          float* __restrict__ out) {
    __shared__ float red[64][9];
    const int tid = threadIdx.x;
    const int b = tid >> 3, p = tid & 7;
    const int k0 = p * 64;
    float s = 0.f;
    #pragma unroll 8
    for (int k = 0; k < 64; ++k) s += hfin[(size_t)b * NH + k0 + k] * w_fc[k0 + k];
    red[b][p] = s;
    __syncthreads();
    if (p == 0) {
        float a = 0.f;
        #pragma unroll
        for (int j = 0; j < 8; ++j) a += red[b][j];
        out[b] = a + b_fc[0];
    }
}

extern "C" void kernel_launch(void* const* d_in, const int* in_sizes, int n_in,
                              void* d_out, int out_size, void* d_ws, size_t ws_size,
                              hipStream_t stream) {
    const float* x     = (const float*)d_in[0];
    const float* W_ih0 = (const float*)d_in[1];
    const float* W_hh0 = (const float*)d_in[2];
    const float* b_ih0 = (const float*)d_in[3];
    const float* b_hh0 = (const float*)d_in[4];
    const float* W_ih1 = (const float*)d_in[5];
    const float* W_hh1 = (const float*)d_in[6];
    const float* b_ih1 = (const float*)d_in[7];
    const float* b_hh1 = (const float*)d_in[8];
    const float* W_fc  = (const float*)d_in[9];
    const float* b_fc  = (const float*)d_in[10];

    // workspace layout (bytes); total ~33.9 MB
    char* ws = (char*)d_ws;
    __bf16*  h0_all = (__bf16*)(ws);                       // 512*64*64*8*2 = 33,554,432
    __bf16*  hinit  = (__bf16*)(ws + 33554432);            // 64*64*8*2 = 65,536
    __bf16*  hs1    = (__bf16*)(ws + 33554432 + 65536);    // 2*64*64*8*2 = 131,072
    float*   hfin   = (float*) (ws + 33554432 + 196608);   // 64*512*4 = 131,072
    unsigned* cnt0  = (unsigned*)(ws + 33554432 + 327680); // 512*16 u32 = 32,768
    unsigned* cnt1  = cnt0 + NT * 16;                      // 32,768

    prep_kernel<<<dim3(256), dim3(256), 0, stream>>>(
        (unsigned short*)hinit, (unsigned short*)hs1, cnt0);

    lstm_fused_kernel<<<dim3(2 * NWG), dim3(512), 0, stream>>>(
        W_ih0, W_hh0, b_ih0, b_hh0, W_ih1, W_hh1, b_ih1, b_hh1,
        x, h0_all, hinit, hs1, hfin, cnt0, cnt1);

    fc_kernel<<<dim3(1), dim3(512), 0, stream>>>(hfin, W_fc, b_fc, (float*)d_out);
}